// Round 2
// baseline (375.744 us; speedup 1.0000x reference)
//
#include <hip/hip_runtime.h>
#include <math.h>

#define NB  8
#define CIN 64
#define HH  112
#define WW  112
#define OC  64
#define HWSZ (HH*WW)
#define KT  576          // C * 9
#define KP  584          // padded LDS row (16B-aligned stride, breaks pow2 banking)
#define PT  16           // positions (wo) per block

typedef unsigned short u16;
typedef __attribute__((ext_vector_type(8))) short short8;
typedef __attribute__((ext_vector_type(4))) float floatx4;

__device__ __forceinline__ u16 f2bf(float f) {
    unsigned int i = __float_as_uint(f);
    unsigned int r = i + 0x7fffu + ((i >> 16) & 1u);   // RNE
    return (u16)(r >> 16);
}

__global__ __launch_bounds__(256) void dcn_fused(
    const float* __restrict__ x,     // [8][64][112][112]
    const float* __restrict__ wgt,   // [64][64][3][3]
    const float* __restrict__ bias,  // [64]
    const float* __restrict__ offw,  // [27][64][3][3]
    const float* __restrict__ offb,  // [27]
    float* __restrict__ out)         // [8][64][112][112]
{
    __shared__ u16   xv[PT][KP];     // im2col tile (bf16), then reused for sampled val
    __shared__ float raws[32][PT];   // offset-conv output (27 real channels)
    __shared__ float w4s[144][4];    // bilinear corner weights (mask folded in)
    __shared__ int   o4s[144][4];    // clamped corner spatial offsets

    const int tid  = threadIdx.x;
    const int wo0  = blockIdx.x * PT;
    const int ho   = blockIdx.y;
    const int n    = blockIdx.z;
    const int pos  = tid & 15;
    const int cg   = tid >> 4;       // 0..15, channel group
    const int lane = tid & 63;
    const int wid  = tid >> 6;

    // ---- step 1: regular im2col of x into LDS (bf16) for the offset-predictor conv ----
    {
        const float* xb = x + (size_t)(n*CIN + cg) * HWSZ;
        const int xx0 = wo0 + pos - 1;
        #pragma unroll
        for (int t = 0; t < 9; ++t) {
            const int ty = t / 3, tx = t - 3*ty;
            const int y  = ho - 1 + ty;
            const int xx = xx0 + tx;
            const bool inb = ((unsigned)y < HH) && ((unsigned)xx < WW);
            const int sp = y * WW + xx;
            #pragma unroll
            for (int cc = 0; cc < 4; ++cc) {
                float v = 0.f;
                if (inb) v = xb[cc*16*HWSZ + sp];
                xv[pos][(cg + 16*cc)*9 + t] = f2bf(v);
            }
        }
    }
    __syncthreads();

    // ---- step 2: offset conv via MFMA (waves 0,1; A rows 27..31 are zero) ----
    if (wid < 2) {
        const int m = lane & 15;     // A row within tile / D col (pos)
        const int q = lane >> 4;     // quad -> k sub-block / D row group
        const int arow = wid*16 + m;
        const float* wr = offw + arow*KT + q*8;
        floatx4 acc = {0.f, 0.f, 0.f, 0.f};
        for (int k0 = 0; k0 < KT; k0 += 32) {
            short8 a = {0,0,0,0,0,0,0,0};
            if (arow < 27) {
                #pragma unroll
                for (int j = 0; j < 8; ++j) a[j] = (short)f2bf(wr[k0 + j]);
            }
            short8 b = *(const short8*)(&xv[m][k0 + q*8]);
            acc = __builtin_amdgcn_mfma_f32_16x16x32_bf16(a, b, acc, 0, 0, 0);
        }
        #pragma unroll
        for (int r = 0; r < 4; ++r) {
            const int grow = wid*16 + q*4 + r;
            const float bb = (grow < 27) ? offb[grow] : 0.f;
            raws[grow][m] = acc[r] + bb;
        }
    }
    __syncthreads();

    // ---- step 3: bilinear coefficients per (tap, pos) ----
    if (tid < 144) {
        const int t = tid >> 4;      // 0..8
        const int p = tid & 15;
        const int ty = t / 3, tx = t - 3*ty;
        // channel layout: raw[2t]=dy, raw[2t+1]=dx, raw[18+t]=mask logit
        const float py = raws[2*t][p]     + (float)(ho - 1 + ty);
        const float px = raws[2*t + 1][p] + (float)(wo0 + p - 1 + tx);
        const float mk = 1.f / (1.f + expf(-raws[18 + t][p]));
        const float y0f = floorf(py), x0f = floorf(px);
        const float fy = py - y0f, fx = px - x0f;
        const int y0 = (int)y0f, xi0 = (int)x0f;
        const float gy = 1.f - fy, gx = 1.f - fx;
        const bool vy0 = (unsigned)y0       < HH;
        const bool vy1 = (unsigned)(y0 + 1) < HH;
        const bool vx0 = (unsigned)xi0       < WW;
        const bool vx1 = (unsigned)(xi0 + 1) < WW;
        w4s[tid][0] = (vy0 && vx0) ? gy*gx*mk : 0.f;
        w4s[tid][1] = (vy0 && vx1) ? gy*fx*mk : 0.f;
        w4s[tid][2] = (vy1 && vx0) ? fy*gx*mk : 0.f;
        w4s[tid][3] = (vy1 && vx1) ? fy*fx*mk : 0.f;
        const int yc0 = min(max(y0, 0), HH-1), yc1 = min(max(y0+1, 0), HH-1);
        const int xc0 = min(max(xi0, 0), WW-1), xc1 = min(max(xi0+1, 0), WW-1);
        o4s[tid][0] = yc0*WW + xc0;
        o4s[tid][1] = yc0*WW + xc1;
        o4s[tid][2] = yc1*WW + xc0;
        o4s[tid][3] = yc1*WW + xc1;
    }
    __syncthreads();

    // ---- step 4: deformable bilinear sampling * mask -> val (reuses xv, bf16) ----
    {
        const float* xb = x + (size_t)(n*CIN + cg) * HWSZ;
        #pragma unroll
        for (int t = 0; t < 9; ++t) {
            const int ci = t*16 + pos;
            const float w00 = w4s[ci][0], w01 = w4s[ci][1];
            const float w10 = w4s[ci][2], w11 = w4s[ci][3];
            const int o00 = o4s[ci][0], o01 = o4s[ci][1];
            const int o10 = o4s[ci][2], o11 = o4s[ci][3];
            #pragma unroll
            for (int cc = 0; cc < 4; ++cc) {
                const float* xc = xb + cc*16*HWSZ;
                const float v = w00 * xc[o00] + w01 * xc[o01]
                              + w10 * xc[o10] + w11 * xc[o11];
                xv[pos][(cg + 16*cc)*9 + t] = f2bf(v);
            }
        }
    }
    __syncthreads();

    // ---- step 5: main conv via MFMA: D[o][pos] = sum_k W[o][k] * val[k][pos] ----
    {
        const int m = lane & 15;
        const int q = lane >> 4;
        const int ob = wid * 16;
        const float* wr = wgt + (ob + m)*KT + q*8;
        floatx4 acc = {0.f, 0.f, 0.f, 0.f};
        for (int k0 = 0; k0 < KT; k0 += 32) {
            short8 a;
            #pragma unroll
            for (int j = 0; j < 8; ++j) a[j] = (short)f2bf(wr[k0 + j]);
            short8 b = *(const short8*)(&xv[m][k0 + q*8]);
            acc = __builtin_amdgcn_mfma_f32_16x16x32_bf16(a, b, acc, 0, 0, 0);
        }
        const int wo = wo0 + m;
        #pragma unroll
        for (int r = 0; r < 4; ++r) {
            const int o = ob + q*4 + r;
            const float res = acc[r] + bias[o];
            out[(((size_t)n*OC + o)*HH + ho)*WW + wo] = res;
        }
    }
}

extern "C" void kernel_launch(void* const* d_in, const int* in_sizes, int n_in,
                              void* d_out, int out_size, void* d_ws, size_t ws_size,
                              hipStream_t stream)
{
    const float* x    = (const float*)d_in[0];
    const float* wgt  = (const float*)d_in[1];
    const float* bias = (const float*)d_in[2];
    const float* offw = (const float*)d_in[3];
    const float* offb = (const float*)d_in[4];
    float* out = (float*)d_out;
    dim3 grid(WW / PT, HH, NB);   // (7, 112, 8) = 6272 blocks
    dcn_fused<<<grid, 256, 0, stream>>>(x, wgt, bias, offw, offb, out);
}

// Round 3
// 233.209 us; speedup vs baseline: 1.6112x; 1.6112x over previous
//
#include <hip/hip_runtime.h>
#include <math.h>

#define NB  8
#define CIN 64
#define HH  112
#define WW  112
#define OC  64
#define HWSZ (HH*WW)
#define KT  576          // 9 taps * 64 ch, k = t*64 + c ordering
#define KP  584          // padded LDS row in u16 (1168 B: 16B-aligned, banks spread)
#define PT  16           // positions (wo) per block

typedef unsigned short u16;
typedef __attribute__((ext_vector_type(8))) short short8;
typedef __attribute__((ext_vector_type(4))) float floatx4;

#define XT_ELEMS (NB*HWSZ*CIN)     // 6,422,528 u16
#define WSWZ_ELEMS (18*4*64*8)     // 36,864 u16
#define OSWZ_ELEMS (18*4*32*8)     // 18,432 u16

__device__ __forceinline__ u16 f2bf(float f) {
    unsigned int i = __float_as_uint(f);
    unsigned int r = i + 0x7fffu + ((i >> 16) & 1u);   // RNE
    return (u16)(r >> 16);
}

// ---------- prep 1: NCHW fp32 -> NHWC bf16 transpose of x ----------
__global__ __launch_bounds__(256) void transpose_k(
    const float* __restrict__ x, u16* __restrict__ xt)
{
    __shared__ float t[64][65];
    const int n   = blockIdx.y;
    const int hw0 = blockIdx.x * 64;
    const int tid = threadIdx.x;
    const int wv  = tid & 63;
    const int g   = tid >> 6;
    #pragma unroll
    for (int i = 0; i < 16; ++i) {
        const int c = i*4 + g;
        t[c][wv] = x[((size_t)n*CIN + c)*HWSZ + hw0 + wv];
    }
    __syncthreads();
    #pragma unroll
    for (int i = 0; i < 16; ++i) {
        const int hw = i*4 + g;
        xt[((size_t)n*HWSZ + hw0 + hw)*CIN + wv] = f2bf(t[wv][hw]);
    }
}

// ---------- prep 2: weights -> bf16 A-fragment swizzle (k = t*64+c) ----------
__global__ __launch_bounds__(256) void wswz_k(
    const float* __restrict__ wgt, const float* __restrict__ offw,
    u16* __restrict__ wswz, u16* __restrict__ oswz)
{
    const int gid = blockIdx.x * 256 + threadIdx.x;
    if (gid < WSWZ_ELEMS) {
        const int j = gid & 7, o = (gid >> 3) & 63, q = (gid >> 9) & 3, s = gid >> 11;
        const int k = s*32 + q*8 + j;
        const int c = k & 63, t = k >> 6;
        wswz[gid] = f2bf(wgt[o*576 + c*9 + t]);
    } else {
        const int g2 = gid - WSWZ_ELEMS;
        const int j = g2 & 7, r = (g2 >> 3) & 31, q = (g2 >> 8) & 3, s = g2 >> 10;
        const int k = s*32 + q*8 + j;
        const int c = k & 63, t = k >> 6;
        oswz[g2] = (r < 27) ? f2bf(offw[r*576 + c*9 + t]) : (u16)0;
    }
}

// ---------- main fused kernel ----------
__global__ __launch_bounds__(256) void dcn_fused(
    const u16*  __restrict__ xt,    // [8][12544][64] bf16 NHWC
    const u16*  __restrict__ wswz,  // swizzled main weights
    const u16*  __restrict__ oswz,  // swizzled offset weights (rows 27..31 zero)
    const float* __restrict__ bias,
    const float* __restrict__ offb,
    float* __restrict__ out)
{
    __shared__ u16   xv[PT][KP];     // B tile (bf16): im2col, then sampled val
    __shared__ float raws[32][PT];   // offset-conv output (27 real channels)
    __shared__ float w4s[144][4];    // bilinear corner weights (mask folded in)
    __shared__ int   o4s[144][4];    // clamped corner offsets, pre-scaled *64

    const int tid  = threadIdx.x;
    const int wo0  = blockIdx.x * PT;
    const int ho   = blockIdx.y;
    const int n    = blockIdx.z;
    const int pos  = tid & 15;
    const int cg   = tid >> 4;       // 0..15, channel group of 4
    const int lane = tid & 63;
    const int wid  = tid >> 6;

    const u16* xtn = xt + (size_t)n * HWSZ * CIN;

    // ---- step 1: im2col of x (zero-padded) into LDS, k = t*64+c ----
    {
        const int xx0 = wo0 + pos - 1;
        #pragma unroll
        for (int t = 0; t < 9; ++t) {
            const int ty = t / 3, tx = t - 3*ty;
            const int y  = ho - 1 + ty;
            const int xx = xx0 + tx;
            uint2 v = {0u, 0u};
            if (((unsigned)y < HH) && ((unsigned)xx < WW))
                v = *(const uint2*)(xtn + (y*WW + xx)*CIN + cg*4);
            *(uint2*)(&xv[pos][t*64 + cg*4]) = v;
        }
    }
    __syncthreads();

    // ---- step 2: offset conv via MFMA (waves 0,1 handle A rows 0..31) ----
    if (wid < 2) {
        const int m = lane & 15;
        const int q = lane >> 4;
        floatx4 acc = {0.f, 0.f, 0.f, 0.f};
        #pragma unroll 3
        for (int s = 0; s < 18; ++s) {
            short8 a = *(const short8*)(oswz + (s*4 + q)*256 + (wid*16 + m)*8);
            short8 b = *(const short8*)(&xv[m][s*32 + q*8]);
            acc = __builtin_amdgcn_mfma_f32_16x16x32_bf16(a, b, acc, 0, 0, 0);
        }
        #pragma unroll
        for (int r = 0; r < 4; ++r) {
            const int grow = wid*16 + q*4 + r;
            raws[grow][m] = acc[r] + ((grow < 27) ? offb[grow] : 0.f);
        }
    }
    __syncthreads();

    // ---- step 3: bilinear coefficients per (tap, pos) ----
    if (tid < 144) {
        const int t = tid >> 4;
        const int p = tid & 15;
        const int ty = t / 3, tx = t - 3*ty;
        const float py = raws[2*t][p]     + (float)(ho - 1 + ty);
        const float px = raws[2*t + 1][p] + (float)(wo0 + p - 1 + tx);
        const float mk = 1.f / (1.f + expf(-raws[18 + t][p]));
        const float y0f = floorf(py), x0f = floorf(px);
        const float fy = py - y0f, fx = px - x0f;
        const int y0 = (int)y0f, xi0 = (int)x0f;
        const float gy = 1.f - fy, gx = 1.f - fx;
        const bool vy0 = (unsigned)y0       < HH;
        const bool vy1 = (unsigned)(y0 + 1) < HH;
        const bool vx0 = (unsigned)xi0       < WW;
        const bool vx1 = (unsigned)(xi0 + 1) < WW;
        w4s[tid][0] = (vy0 && vx0) ? gy*gx*mk : 0.f;
        w4s[tid][1] = (vy0 && vx1) ? gy*fx*mk : 0.f;
        w4s[tid][2] = (vy1 && vx0) ? fy*gx*mk : 0.f;
        w4s[tid][3] = (vy1 && vx1) ? fy*fx*mk : 0.f;
        const int yc0 = min(max(y0, 0), HH-1), yc1 = min(max(y0+1, 0), HH-1);
        const int xc0 = min(max(xi0, 0), WW-1), xc1 = min(max(xi0+1, 0), WW-1);
        o4s[tid][0] = (yc0*WW + xc0) * CIN;
        o4s[tid][1] = (yc0*WW + xc1) * CIN;
        o4s[tid][2] = (yc1*WW + xc0) * CIN;
        o4s[tid][3] = (yc1*WW + xc1) * CIN;
    }
    __syncthreads();

    // ---- step 4: bilinear sampling * mask -> val tile (bf16, k = t*64+c) ----
    {
        const u16* xc4 = xtn + cg*4;
        #pragma unroll
        for (int t = 0; t < 9; ++t) {
            const int ci = t*16 + pos;
            const float w00 = w4s[ci][0], w01 = w4s[ci][1];
            const float w10 = w4s[ci][2], w11 = w4s[ci][3];
            const uint2 r00 = *(const uint2*)(xc4 + o4s[ci][0]);
            const uint2 r01 = *(const uint2*)(xc4 + o4s[ci][1]);
            const uint2 r10 = *(const uint2*)(xc4 + o4s[ci][2]);
            const uint2 r11 = *(const uint2*)(xc4 + o4s[ci][3]);
            float v[4];
            v[0] = w00 * __uint_as_float(r00.x << 16)
                 + w01 * __uint_as_float(r01.x << 16)
                 + w10 * __uint_as_float(r10.x << 16)
                 + w11 * __uint_as_float(r11.x << 16);
            v[1] = w00 * __uint_as_float(r00.x & 0xffff0000u)
                 + w01 * __uint_as_float(r01.x & 0xffff0000u)
                 + w10 * __uint_as_float(r10.x & 0xffff0000u)
                 + w11 * __uint_as_float(r11.x & 0xffff0000u);
            v[2] = w00 * __uint_as_float(r00.y << 16)
                 + w01 * __uint_as_float(r01.y << 16)
                 + w10 * __uint_as_float(r10.y << 16)
                 + w11 * __uint_as_float(r11.y << 16);
            v[3] = w00 * __uint_as_float(r00.y & 0xffff0000u)
                 + w01 * __uint_as_float(r01.y & 0xffff0000u)
                 + w10 * __uint_as_float(r10.y & 0xffff0000u)
                 + w11 * __uint_as_float(r11.y & 0xffff0000u);
            uint2 o;
            o.x = (unsigned)f2bf(v[0]) | ((unsigned)f2bf(v[1]) << 16);
            o.y = (unsigned)f2bf(v[2]) | ((unsigned)f2bf(v[3]) << 16);
            *(uint2*)(&xv[pos][t*64 + cg*4]) = o;
        }
    }
    __syncthreads();

    // ---- step 5: main conv via MFMA: D[o][pos] ----
    {
        const int m = lane & 15;
        const int q = lane >> 4;
        const int ob = wid * 16;
        floatx4 acc = {0.f, 0.f, 0.f, 0.f};
        #pragma unroll 3
        for (int s = 0; s < 18; ++s) {
            short8 a = *(const short8*)(wswz + (s*4 + q)*512 + (ob + m)*8);
            short8 b = *(const short8*)(&xv[m][s*32 + q*8]);
            acc = __builtin_amdgcn_mfma_f32_16x16x32_bf16(a, b, acc, 0, 0, 0);
        }
        const int wo = wo0 + m;
        #pragma unroll
        for (int r = 0; r < 4; ++r) {
            const int o = ob + q*4 + r;
            out[(((size_t)n*OC + o)*HH + ho)*WW + wo] = acc[r] + bias[o];
        }
    }
}

extern "C" void kernel_launch(void* const* d_in, const int* in_sizes, int n_in,
                              void* d_out, int out_size, void* d_ws, size_t ws_size,
                              hipStream_t stream)
{
    const float* x    = (const float*)d_in[0];
    const float* wgt  = (const float*)d_in[1];
    const float* bias = (const float*)d_in[2];
    const float* offw = (const float*)d_in[3];
    const float* offb = (const float*)d_in[4];
    float* out = (float*)d_out;

    u16* xt   = (u16*)d_ws;
    u16* wswz = xt + XT_ELEMS;
    u16* oswz = wswz + WSWZ_ELEMS;

    transpose_k<<<dim3(HWSZ/64, NB), 256, 0, stream>>>(x, xt);
    wswz_k<<<dim3((WSWZ_ELEMS + OSWZ_ELEMS)/256), 256, 0, stream>>>(wgt, offw, wswz, oswz);
    dcn_fused<<<dim3(WW/PT, HH, NB), 256, 0, stream>>>(xt, wswz, oswz, bias, offb, out);
}

// Round 4
// 187.072 us; speedup vs baseline: 2.0085x; 1.2466x over previous
//
#include <hip/hip_runtime.h>
#include <math.h>

#define NB  8
#define CIN 64
#define HH  112
#define WW  112
#define OC  64
#define HWSZ (HH*WW)
#define NPOS (NB*HWSZ)           // 100352 output positions

typedef unsigned short u16;
typedef __attribute__((ext_vector_type(8))) short short8;
typedef __attribute__((ext_vector_type(4))) float floatx4;

#define XT_ELEMS   (NB*HWSZ*CIN)   // 6,422,528 u16 (12.25 MB)
#define WSWZ_ELEMS (18*4*64*8)     // 36,864 u16
#define OSWZ_ELEMS (18*4*32*8)     // 18,432 u16

__device__ __forceinline__ u16 f2bf(float f) {
    unsigned int i = __float_as_uint(f);
    unsigned int r = i + 0x7fffu + ((i >> 16) & 1u);   // RNE
    return (u16)(r >> 16);
}
#define BLO(uu) __uint_as_float((uu) << 16)
#define BHI(uu) __uint_as_float((uu) & 0xffff0000u)

union CV { uint4 u; short8 s; };

// ---------- prep 1: NCHW fp32 -> NHWC bf16 transpose of x ----------
__global__ __launch_bounds__(256) void transpose_k(
    const float* __restrict__ x, u16* __restrict__ xt)
{
    __shared__ float t[64][65];
    const int n   = blockIdx.y;
    const int hw0 = blockIdx.x * 64;
    const int tid = threadIdx.x;
    const int wv  = tid & 63;
    const int g   = tid >> 6;
    #pragma unroll
    for (int i = 0; i < 16; ++i) {
        const int c = i*4 + g;
        t[c][wv] = x[((size_t)n*CIN + c)*HWSZ + hw0 + wv];
    }
    __syncthreads();
    #pragma unroll
    for (int i = 0; i < 4; ++i) {
        const int unit = i*256 + tid;
        const int cg = unit & 15;       // channel group of 4
        const int hw = unit >> 4;       // 0..63
        uint2 o;
        o.x = (unsigned)f2bf(t[cg*4+0][hw]) | ((unsigned)f2bf(t[cg*4+1][hw]) << 16);
        o.y = (unsigned)f2bf(t[cg*4+2][hw]) | ((unsigned)f2bf(t[cg*4+3][hw]) << 16);
        *(uint2*)(xt + ((size_t)n*HWSZ + hw0 + hw)*CIN + cg*4) = o;
    }
}

// ---------- prep 2: weights -> bf16 A-fragment swizzle (k = t*64+c) ----------
__global__ __launch_bounds__(256) void wswz_k(
    const float* __restrict__ wgt, const float* __restrict__ offw,
    u16* __restrict__ wswz, u16* __restrict__ oswz)
{
    const int gid = blockIdx.x * 256 + threadIdx.x;
    if (gid < WSWZ_ELEMS) {
        const int j = gid & 7, o = (gid >> 3) & 63, q = (gid >> 9) & 3, s = gid >> 11;
        const int k = s*32 + q*8 + j;
        const int c = k & 63, t = k >> 6;
        wswz[gid] = f2bf(wgt[o*576 + c*9 + t]);
    } else {
        const int g2 = gid - WSWZ_ELEMS;
        const int j = g2 & 7, r = (g2 >> 3) & 31, q = (g2 >> 8) & 3, s = g2 >> 10;
        const int k = s*32 + q*8 + j;
        const int c = k & 63, t = k >> 6;
        oswz[g2] = (r < 27) ? f2bf(offw[r*576 + c*9 + t]) : (u16)0;
    }
}

// ---------- k1: offset conv (direct global B-frags) -> sampling table ----------
// tbl[pos][tap] = float4(py, px, sigmoid(mask), 0)
__global__ __launch_bounds__(256) void offsets_k(
    const u16*  __restrict__ xt,
    const u16*  __restrict__ oswz,
    const float* __restrict__ offb,
    float4* __restrict__ tbl)
{
    __shared__ float raws[4][32][16];
    const int tid  = threadIdx.x;
    const int lane = tid & 63;
    const int wid  = tid >> 6;
    const int m    = lane & 15;
    const int q    = lane >> 4;

    const int pos0w = blockIdx.x*64 + wid*16;
    const int n   = pos0w / HWSZ;
    const int rem = pos0w - n*HWSZ;
    const int ho  = rem / WW;
    const int wo0 = rem - ho*WW;
    const u16* xtn = xt + (size_t)n * HWSZ * CIN;

    floatx4 acc0 = {0.f,0.f,0.f,0.f}, acc1 = {0.f,0.f,0.f,0.f};
    #pragma unroll
    for (int s = 0; s < 18; ++s) {
        const int t  = s >> 1;
        const int ty = t / 3, tx = t - 3*ty;
        const int y  = ho - 1 + ty;
        const int xx = wo0 + m - 1 + tx;
        const int ch = (s & 1)*32 + q*8;
        uint4 bu = {0u,0u,0u,0u};
        if (((unsigned)y < HH) && ((unsigned)xx < WW))
            bu = *(const uint4*)(xtn + (y*WW + xx)*CIN + ch);
        CV cb; cb.u = bu;
        const u16* ap = oswz + (s*4 + q)*256 + m*8;
        short8 a0 = *(const short8*)(ap);
        short8 a1 = *(const short8*)(ap + 128);
        acc0 = __builtin_amdgcn_mfma_f32_16x16x32_bf16(a0, cb.s, acc0, 0, 0, 0);
        acc1 = __builtin_amdgcn_mfma_f32_16x16x32_bf16(a1, cb.s, acc1, 0, 0, 0);
    }
    #pragma unroll
    for (int r = 0; r < 4; ++r) {
        raws[wid][q*4 + r][m]      = acc0[r];
        raws[wid][16 + q*4 + r][m] = acc1[r];
    }
    __syncthreads();

    for (int u = tid; u < 576; u += 256) {
        const int posl = u / 9;
        const int t    = u - posl*9;
        const int w2   = posl >> 4, m2 = posl & 15;
        const int posg = blockIdx.x*64 + posl;
        const int n2   = posg / HWSZ;
        const int rm2  = posg - n2*HWSZ;
        const int ho2  = rm2 / WW;
        const int wo2  = rm2 - ho2*WW;
        const int ty = t / 3, tx = t - 3*ty;
        const float py = raws[w2][2*t][m2]     + offb[2*t]     + (float)(ho2 - 1 + ty);
        const float px = raws[w2][2*t + 1][m2] + offb[2*t + 1] + (float)(wo2 - 1 + tx);
        const float mk = 1.f / (1.f + expf(-(raws[w2][18 + t][m2] + offb[18 + t])));
        float4 o; o.x = py; o.y = px; o.z = mk; o.w = 0.f;
        tbl[posg*9 + t] = o;
    }
}

// ---------- k2: gather + main conv, zero LDS, zero barriers ----------
__global__ __launch_bounds__(256) void main_k(
    const u16*  __restrict__ xt,
    const u16*  __restrict__ wswz,
    const float* __restrict__ bias,
    const float4* __restrict__ tbl,
    float* __restrict__ out)
{
    const int tid  = threadIdx.x;
    const int lane = tid & 63;
    const int wid  = tid >> 6;
    const int m    = lane & 15;
    const int q    = lane >> 4;

    const int pos0w = blockIdx.x*64 + wid*16;
    const int n   = pos0w / HWSZ;
    const int rem = pos0w - n*HWSZ;
    const int ho  = rem / WW;
    const int wo0 = rem - ho*WW;
    const u16* xtn = xt + (size_t)n * HWSZ * CIN;

    floatx4 acc[4];
    #pragma unroll
    for (int i = 0; i < 4; ++i) acc[i] = (floatx4){0.f,0.f,0.f,0.f};

    #pragma unroll 3
    for (int t = 0; t < 9; ++t) {
        const float4 pp = tbl[(pos0w + m)*9 + t];
        const float py = pp.x, px = pp.y, mk = pp.z;
        const float y0f = floorf(py), x0f = floorf(px);
        const float fy = py - y0f, fx = px - x0f;
        const int y0 = (int)y0f, x0 = (int)x0f;
        const float gy = 1.f - fy, gx = 1.f - fx;
        const bool vy0 = (unsigned)y0       < HH;
        const bool vy1 = (unsigned)(y0 + 1) < HH;
        const bool vx0 = (unsigned)x0       < WW;
        const bool vx1 = (unsigned)(x0 + 1) < WW;
        const float w00 = (vy0 && vx0) ? gy*gx*mk : 0.f;
        const float w01 = (vy0 && vx1) ? gy*fx*mk : 0.f;
        const float w10 = (vy1 && vx0) ? fy*gx*mk : 0.f;
        const float w11 = (vy1 && vx1) ? fy*fx*mk : 0.f;
        const int yc0 = min(max(y0, 0), HH-1),   yc1 = min(max(y0+1, 0), HH-1);
        const int xc0 = min(max(x0, 0), WW-1),   xc1 = min(max(x0+1, 0), WW-1);
        const int o00 = (yc0*WW + xc0)*CIN, o01 = (yc0*WW + xc1)*CIN;
        const int o10 = (yc1*WW + xc0)*CIN, o11 = (yc1*WW + xc1)*CIN;

        #pragma unroll
        for (int h = 0; h < 2; ++h) {
            const int ch = h*32 + q*8;
            const uint4 r00 = *(const uint4*)(xtn + o00 + ch);
            const uint4 r01 = *(const uint4*)(xtn + o01 + ch);
            const uint4 r10 = *(const uint4*)(xtn + o10 + ch);
            const uint4 r11 = *(const uint4*)(xtn + o11 + ch);
            float v0 = w00*BLO(r00.x) + w01*BLO(r01.x) + w10*BLO(r10.x) + w11*BLO(r11.x);
            float v1 = w00*BHI(r00.x) + w01*BHI(r01.x) + w10*BHI(r10.x) + w11*BHI(r11.x);
            float v2 = w00*BLO(r00.y) + w01*BLO(r01.y) + w10*BLO(r10.y) + w11*BLO(r11.y);
            float v3 = w00*BHI(r00.y) + w01*BHI(r01.y) + w10*BHI(r10.y) + w11*BHI(r11.y);
            float v4 = w00*BLO(r00.z) + w01*BLO(r01.z) + w10*BLO(r10.z) + w11*BLO(r11.z);
            float v5 = w00*BHI(r00.z) + w01*BHI(r01.z) + w10*BHI(r10.z) + w11*BHI(r11.z);
            float v6 = w00*BLO(r00.w) + w01*BLO(r01.w) + w10*BLO(r10.w) + w11*BLO(r11.w);
            float v7 = w00*BHI(r00.w) + w01*BHI(r01.w) + w10*BHI(r10.w) + w11*BHI(r11.w);
            CV cb;
            cb.u.x = (unsigned)f2bf(v0) | ((unsigned)f2bf(v1) << 16);
            cb.u.y = (unsigned)f2bf(v2) | ((unsigned)f2bf(v3) << 16);
            cb.u.z = (unsigned)f2bf(v4) | ((unsigned)f2bf(v5) << 16);
            cb.u.w = (unsigned)f2bf(v6) | ((unsigned)f2bf(v7) << 16);
            const int s = 2*t + h;
            const u16* wp = wswz + (s*4 + q)*512 + m*8;
            acc[0] = __builtin_amdgcn_mfma_f32_16x16x32_bf16(*(const short8*)(wp),       cb.s, acc[0], 0, 0, 0);
            acc[1] = __builtin_amdgcn_mfma_f32_16x16x32_bf16(*(const short8*)(wp + 128), cb.s, acc[1], 0, 0, 0);
            acc[2] = __builtin_amdgcn_mfma_f32_16x16x32_bf16(*(const short8*)(wp + 256), cb.s, acc[2], 0, 0, 0);
            acc[3] = __builtin_amdgcn_mfma_f32_16x16x32_bf16(*(const short8*)(wp + 384), cb.s, acc[3], 0, 0, 0);
        }
    }

    #pragma unroll
    for (int ob = 0; ob < 4; ++ob) {
        #pragma unroll
        for (int r = 0; r < 4; ++r) {
            const int o = ob*16 + q*4 + r;
            out[(((size_t)n*OC + o)*HH + ho)*WW + wo0 + m] = acc[ob][r] + bias[o];
        }
    }
}

extern "C" void kernel_launch(void* const* d_in, const int* in_sizes, int n_in,
                              void* d_out, int out_size, void* d_ws, size_t ws_size,
                              hipStream_t stream)
{
    const float* x    = (const float*)d_in[0];
    const float* wgt  = (const float*)d_in[1];
    const float* bias = (const float*)d_in[2];
    const float* offw = (const float*)d_in[3];
    const float* offb = (const float*)d_in[4];
    float* out = (float*)d_out;

    u16* xt   = (u16*)d_ws;
    u16* wswz = xt + XT_ELEMS;
    u16* oswz = wswz + WSWZ_ELEMS;
    float4* tbl = (float4*)(oswz + OSWZ_ELEMS);   // offset 12,955,648 B (16B-aligned)

    transpose_k<<<dim3(HWSZ/64, NB), 256, 0, stream>>>(x, xt);
    wswz_k<<<dim3((WSWZ_ELEMS + OSWZ_ELEMS)/256), 256, 0, stream>>>(wgt, offw, wswz, oswz);
    offsets_k<<<dim3(NPOS/64), 256, 0, stream>>>(xt, oswz, offb, tbl);
    main_k   <<<dim3(NPOS/64), 256, 0, stream>>>(xt, wswz, bias, tbl, out);
}

// Round 5
// 183.401 us; speedup vs baseline: 2.0488x; 1.0200x over previous
//
#include <hip/hip_runtime.h>
#include <math.h>

#define NB  8
#define CIN 64
#define HH  112
#define WW  112
#define OC  64
#define HWSZ (HH*WW)
#define NPOS (NB*HWSZ)           // 100352 output positions

typedef unsigned short u16;
typedef __attribute__((ext_vector_type(8))) short short8;
typedef __attribute__((ext_vector_type(4))) float floatx4;

#define XT_ELEMS   (NB*HWSZ*CIN)   // 6,422,528 u16 (12.25 MB)
#define WSWZ_ELEMS (18*4*64*8)     // 36,864 u16
#define OSWZ_ELEMS (18*4*32*8)     // 18,432 u16

__device__ __forceinline__ u16 f2bf(float f) {
    unsigned int i = __float_as_uint(f);
    unsigned int r = i + 0x7fffu + ((i >> 16) & 1u);   // RNE
    return (u16)(r >> 16);
}
#define BLO(uu) __uint_as_float((uu) << 16)
#define BHI(uu) __uint_as_float((uu) & 0xffff0000u)

union CV { uint4 u; short8 s; };

struct TapP { int o00, o01, o10, o11; float w00, w01, w10, w11; };

__device__ __forceinline__ TapP mktap(float4 pp) {
    TapP r;
    const float py = pp.x, px = pp.y, mk = pp.z;
    const float y0f = floorf(py), x0f = floorf(px);
    const float fy = py - y0f, fx = px - x0f;
    const int y0 = (int)y0f, x0 = (int)x0f;
    const float gy = 1.f - fy, gx = 1.f - fx;
    const bool vy0 = (unsigned)y0       < HH;
    const bool vy1 = (unsigned)(y0 + 1) < HH;
    const bool vx0 = (unsigned)x0       < WW;
    const bool vx1 = (unsigned)(x0 + 1) < WW;
    r.w00 = (vy0 && vx0) ? gy*gx*mk : 0.f;
    r.w01 = (vy0 && vx1) ? gy*fx*mk : 0.f;
    r.w10 = (vy1 && vx0) ? fy*gx*mk : 0.f;
    r.w11 = (vy1 && vx1) ? fy*fx*mk : 0.f;
    const int yc0 = min(max(y0, 0), HH-1),  yc1 = min(max(y0+1, 0), HH-1);
    const int xc0 = min(max(x0, 0), WW-1),  xc1 = min(max(x0+1, 0), WW-1);
    r.o00 = (yc0*WW + xc0)*CIN;  r.o01 = (yc0*WW + xc1)*CIN;
    r.o10 = (yc1*WW + xc0)*CIN;  r.o11 = (yc1*WW + xc1)*CIN;
    return r;
}

// ---------- prep 1: NCHW fp32 -> NHWC bf16 transpose of x ----------
__global__ __launch_bounds__(256) void transpose_k(
    const float* __restrict__ x, u16* __restrict__ xt)
{
    __shared__ float t[64][65];
    const int n   = blockIdx.y;
    const int hw0 = blockIdx.x * 64;
    const int tid = threadIdx.x;
    const int wv  = tid & 63;
    const int g   = tid >> 6;
    #pragma unroll
    for (int i = 0; i < 16; ++i) {
        const int c = i*4 + g;
        t[c][wv] = x[((size_t)n*CIN + c)*HWSZ + hw0 + wv];
    }
    __syncthreads();
    #pragma unroll
    for (int i = 0; i < 4; ++i) {
        const int unit = i*256 + tid;
        const int cg = unit & 15;
        const int hw = unit >> 4;
        uint2 o;
        o.x = (unsigned)f2bf(t[cg*4+0][hw]) | ((unsigned)f2bf(t[cg*4+1][hw]) << 16);
        o.y = (unsigned)f2bf(t[cg*4+2][hw]) | ((unsigned)f2bf(t[cg*4+3][hw]) << 16);
        *(uint2*)(xt + ((size_t)n*HWSZ + hw0 + hw)*CIN + cg*4) = o;
    }
}

// ---------- prep 2: weights -> bf16 A-fragment swizzle (k = t*64+c) ----------
__global__ __launch_bounds__(256) void wswz_k(
    const float* __restrict__ wgt, const float* __restrict__ offw,
    u16* __restrict__ wswz, u16* __restrict__ oswz)
{
    const int gid = blockIdx.x * 256 + threadIdx.x;
    if (gid < WSWZ_ELEMS) {
        const int j = gid & 7, o = (gid >> 3) & 63, q = (gid >> 9) & 3, s = gid >> 11;
        const int k = s*32 + q*8 + j;
        const int c = k & 63, t = k >> 6;
        wswz[gid] = f2bf(wgt[o*576 + c*9 + t]);
    } else {
        const int g2 = gid - WSWZ_ELEMS;
        const int j = g2 & 7, r = (g2 >> 3) & 31, q = (g2 >> 8) & 3, s = g2 >> 10;
        const int k = s*32 + q*8 + j;
        const int c = k & 63, t = k >> 6;
        oswz[g2] = (r < 27) ? f2bf(offw[r*576 + c*9 + t]) : (u16)0;
    }
}

// ---------- k1: offset conv -> sampling table tbl[t][pos] ----------
__global__ __launch_bounds__(256) void offsets_k(
    const u16*  __restrict__ xt,
    const u16*  __restrict__ oswz,
    const float* __restrict__ offb,
    float4* __restrict__ tbl)
{
    __shared__ float raws[4][32][16];
    const int tid  = threadIdx.x;
    const int lane = tid & 63;
    const int wid  = tid >> 6;
    const int m    = lane & 15;
    const int q    = lane >> 4;

    const int n     = blockIdx.x & 7;                    // XCD-locality swizzle
    const int rem64 = ((blockIdx.x >> 3) * 4 + wid) * 16; // position within image
    const int ho  = rem64 / WW;
    const int wo0 = rem64 - ho*WW;
    const u16* xtn = xt + (size_t)n * HWSZ * CIN;

    // stage 1: issue all 18 B-fragment loads
    uint4 bu[18];
    #pragma unroll
    for (int s = 0; s < 18; ++s) {
        const int t  = s >> 1;
        const int ty = t / 3, tx = t - 3*ty;
        const int y  = ho - 1 + ty;
        const int xx = wo0 + m - 1 + tx;
        const int ch = (s & 1)*32 + q*8;
        uint4 v = {0u,0u,0u,0u};
        if (((unsigned)y < HH) && ((unsigned)xx < WW))
            v = *(const uint4*)(xtn + (y*WW + xx)*CIN + ch);
        bu[s] = v;
    }

    // stage 2: MFMA chain
    floatx4 acc0 = {0.f,0.f,0.f,0.f}, acc1 = {0.f,0.f,0.f,0.f};
    #pragma unroll
    for (int s = 0; s < 18; ++s) {
        CV cb; cb.u = bu[s];
        const u16* ap = oswz + (s*4 + q)*256 + m*8;
        acc0 = __builtin_amdgcn_mfma_f32_16x16x32_bf16(*(const short8*)(ap),       cb.s, acc0, 0, 0, 0);
        acc1 = __builtin_amdgcn_mfma_f32_16x16x32_bf16(*(const short8*)(ap + 128), cb.s, acc1, 0, 0, 0);
    }
    #pragma unroll
    for (int r = 0; r < 4; ++r) {
        raws[wid][q*4 + r][m]      = acc0[r];
        raws[wid][16 + q*4 + r][m] = acc1[r];
    }
    __syncthreads();

    // epilogue: tbl[t][pos], coalesced (576 = 9 taps x 64 positions)
    #pragma unroll
    for (int i = 0; i < 3; ++i) {
        const int u = i*256 + tid;
        if (u < 576) {
            const int t    = u >> 6;          // 0..8
            const int posl = u & 63;
            const int w2   = posl >> 4, m2 = posl & 15;
            const int rl   = (blockIdx.x >> 3)*64 + posl;
            const int ho2  = rl / WW;
            const int wo2  = rl - ho2*WW;
            const int ty = t / 3, tx = t - 3*ty;
            const float py = raws[w2][2*t][m2]     + offb[2*t]     + (float)(ho2 - 1 + ty);
            const float px = raws[w2][2*t + 1][m2] + offb[2*t + 1] + (float)(wo2 - 1 + tx);
            const float mk = 1.f / (1.f + expf(-(raws[w2][18 + t][m2] + offb[18 + t])));
            float4 o; o.x = py; o.y = px; o.z = mk; o.w = 0.f;
            tbl[(size_t)t*NPOS + n*HWSZ + rl] = o;
        }
    }
}

// ---------- k2: gather + main conv, zero LDS, software-pipelined ----------
__global__ __launch_bounds__(256) void main_k(
    const u16*  __restrict__ xt,
    const u16*  __restrict__ wswz,
    const float* __restrict__ bias,
    const float4* __restrict__ tbl,
    float* __restrict__ out)
{
    const int tid  = threadIdx.x;
    const int lane = tid & 63;
    const int wid  = tid >> 6;
    const int m    = lane & 15;
    const int q    = lane >> 4;

    const int n     = blockIdx.x & 7;                    // XCD-locality swizzle
    const int rem64 = ((blockIdx.x >> 3) * 4 + wid) * 16;
    const int ho  = rem64 / WW;
    const int wo0 = rem64 - ho*WW;
    const u16* xtn = xt + (size_t)n * HWSZ * CIN;
    const int posg = n*HWSZ + rem64 + m;                 // this lane's position

    floatx4 acc[4];
    #pragma unroll
    for (int i = 0; i < 4; ++i) acc[i] = (floatx4){0.f,0.f,0.f,0.f};

    // pipeline prologue: tap 0 params + gathers, tap1 table entry in flight
    float4 ppA = tbl[posg];                 // t=0
    float4 ppB = tbl[(size_t)NPOS + posg];  // t=1
    TapP cur = mktap(ppA);
    uint4 g[8];
    #pragma unroll
    for (int h = 0; h < 2; ++h) {
        const int ch = h*32 + q*8;
        g[h*4+0] = *(const uint4*)(xtn + cur.o00 + ch);
        g[h*4+1] = *(const uint4*)(xtn + cur.o01 + ch);
        g[h*4+2] = *(const uint4*)(xtn + cur.o10 + ch);
        g[h*4+3] = *(const uint4*)(xtn + cur.o11 + ch);
    }

    #pragma unroll
    for (int t = 0; t < 9; ++t) {
        TapP nxt;
        uint4 gn[8];
        if (t < 8) {
            nxt = mktap(ppB);
            #pragma unroll
            for (int h = 0; h < 2; ++h) {
                const int ch = h*32 + q*8;
                gn[h*4+0] = *(const uint4*)(xtn + nxt.o00 + ch);
                gn[h*4+1] = *(const uint4*)(xtn + nxt.o01 + ch);
                gn[h*4+2] = *(const uint4*)(xtn + nxt.o10 + ch);
                gn[h*4+3] = *(const uint4*)(xtn + nxt.o11 + ch);
            }
            if (t < 7) ppB = tbl[(size_t)(t+2)*NPOS + posg];
        }
        // process current tap
        #pragma unroll
        for (int h = 0; h < 2; ++h) {
            const uint4 r00 = g[h*4+0], r01 = g[h*4+1], r10 = g[h*4+2], r11 = g[h*4+3];
            const float w00 = cur.w00, w01 = cur.w01, w10 = cur.w10, w11 = cur.w11;
            float v0 = w00*BLO(r00.x) + w01*BLO(r01.x) + w10*BLO(r10.x) + w11*BLO(r11.x);
            float v1 = w00*BHI(r00.x) + w01*BHI(r01.x) + w10*BHI(r10.x) + w11*BHI(r11.x);
            float v2 = w00*BLO(r00.y) + w01*BLO(r01.y) + w10*BLO(r10.y) + w11*BLO(r11.y);
            float v3 = w00*BHI(r00.y) + w01*BHI(r01.y) + w10*BHI(r10.y) + w11*BHI(r11.y);
            float v4 = w00*BLO(r00.z) + w01*BLO(r01.z) + w10*BLO(r10.z) + w11*BLO(r11.z);
            float v5 = w00*BHI(r00.z) + w01*BHI(r01.z) + w10*BHI(r10.z) + w11*BHI(r11.z);
            float v6 = w00*BLO(r00.w) + w01*BLO(r01.w) + w10*BLO(r10.w) + w11*BLO(r11.w);
            float v7 = w00*BHI(r00.w) + w01*BHI(r01.w) + w10*BHI(r10.w) + w11*BHI(r11.w);
            CV cb;
            cb.u.x = (unsigned)f2bf(v0) | ((unsigned)f2bf(v1) << 16);
            cb.u.y = (unsigned)f2bf(v2) | ((unsigned)f2bf(v3) << 16);
            cb.u.z = (unsigned)f2bf(v4) | ((unsigned)f2bf(v5) << 16);
            cb.u.w = (unsigned)f2bf(v6) | ((unsigned)f2bf(v7) << 16);
            const int s = 2*t + h;
            const u16* wp = wswz + (s*4 + q)*512 + m*8;
            acc[0] = __builtin_amdgcn_mfma_f32_16x16x32_bf16(*(const short8*)(wp),       cb.s, acc[0], 0, 0, 0);
            acc[1] = __builtin_amdgcn_mfma_f32_16x16x32_bf16(*(const short8*)(wp + 128), cb.s, acc[1], 0, 0, 0);
            acc[2] = __builtin_amdgcn_mfma_f32_16x16x32_bf16(*(const short8*)(wp + 256), cb.s, acc[2], 0, 0, 0);
            acc[3] = __builtin_amdgcn_mfma_f32_16x16x32_bf16(*(const short8*)(wp + 384), cb.s, acc[3], 0, 0, 0);
        }
        if (t < 8) {
            cur = nxt;
            #pragma unroll
            for (int i = 0; i < 8; ++i) g[i] = gn[i];
        }
    }

    #pragma unroll
    for (int ob = 0; ob < 4; ++ob) {
        #pragma unroll
        for (int r = 0; r < 4; ++r) {
            const int o = ob*16 + q*4 + r;
            out[(((size_t)n*OC + o)*HH + ho)*WW + wo0 + m] = acc[ob][r] + bias[o];
        }
    }
}

extern "C" void kernel_launch(void* const* d_in, const int* in_sizes, int n_in,
                              void* d_out, int out_size, void* d_ws, size_t ws_size,
                              hipStream_t stream)
{
    const float* x    = (const float*)d_in[0];
    const float* wgt  = (const float*)d_in[1];
    const float* bias = (const float*)d_in[2];
    const float* offw = (const float*)d_in[3];
    const float* offb = (const float*)d_in[4];
    float* out = (float*)d_out;

    u16* xt   = (u16*)d_ws;
    u16* wswz = xt + XT_ELEMS;
    u16* oswz = wswz + WSWZ_ELEMS;
    float4* tbl = (float4*)(oswz + OSWZ_ELEMS);   // 16B-aligned

    transpose_k<<<dim3(HWSZ/64, NB), 256, 0, stream>>>(x, xt);
    wswz_k<<<dim3((WSWZ_ELEMS + OSWZ_ELEMS)/256), 256, 0, stream>>>(wgt, offw, wswz, oswz);
    offsets_k<<<dim3(NPOS/64), 256, 0, stream>>>(xt, oswz, offb, tbl);
    main_k   <<<dim3(NPOS/64), 256, 0, stream>>>(xt, wswz, bias, tbl, out);
}

// Round 7
// 175.593 us; speedup vs baseline: 2.1399x; 1.0445x over previous
//
#include <hip/hip_runtime.h>
#include <hip/hip_bf16.h>
#include <hip/hip_fp16.h>
#include <math.h>

#define NB  8
#define CIN 64
#define HH  112
#define WW  112
#define OC  64
#define HWSZ (HH*WW)
#define NPOS (NB*HWSZ)

typedef unsigned short u16;
typedef __attribute__((ext_vector_type(8))) short short8;
typedef __attribute__((ext_vector_type(4))) float floatx4;

#define XT_ELEMS   (NB*HWSZ*CIN)   // 6,422,528 u16 (12.25 MB)
#define WSWZ_ELEMS (18*4*64*8)     // 36,864 u16
#define OSWZ_ELEMS (18*4*32*8)     // 18,432 u16

__device__ __forceinline__ u16 f2bf(float f) {
    unsigned int i = __float_as_uint(f);
    unsigned int r = i + 0x7fffu + ((i >> 16) & 1u);   // RNE
    return (u16)(r >> 16);
}
__device__ __forceinline__ unsigned pk2bf(float lo, float hi) {
    union { __hip_bfloat162 b; unsigned u; } cv;
    cv.b = __float22bfloat162_rn(float2{lo, hi});      // v_cvt_pk_bf16_f32
    return cv.u;
}
#define BLO(uu) __uint_as_float((uu) << 16)
#define BHI(uu) __uint_as_float((uu) & 0xffff0000u)

union CV { uint4 u; short8 s; };

struct Tap { int o00, o01, o10, o11; float w00, w01, w10, w11; };

__device__ __forceinline__ Tap unpackP(uint4 P) {
    Tap t;
    const int o00 = (int)(P.x & 0xFFFFFu);
    const int dx  = (int)((P.x >> 30) & 1u) << 6;      // 0 or 64  (=CIN)
    const int dy  = (int)(P.x >> 31) * (WW*CIN);       // 0 or 7168
    t.o00 = o00; t.o01 = o00 + dx; t.o10 = o00 + dy; t.o11 = o00 + dx + dy;
    t.w00 = __half2float(__ushort_as_half((u16)(P.y & 0xFFFFu)));
    t.w01 = __half2float(__ushort_as_half((u16)(P.y >> 16)));
    t.w10 = __half2float(__ushort_as_half((u16)(P.z & 0xFFFFu)));
    t.w11 = __half2float(__ushort_as_half((u16)(P.z >> 16)));
    return t;
}

// ---------- prep 1: NCHW fp32 -> NHWC bf16 transpose of x ----------
__global__ __launch_bounds__(256) void transpose_k(
    const float* __restrict__ x, u16* __restrict__ xt)
{
    __shared__ float t[64][65];
    const int n   = blockIdx.y;
    const int hw0 = blockIdx.x * 64;
    const int tid = threadIdx.x;
    const int wv  = tid & 63;
    const int g   = tid >> 6;
    #pragma unroll
    for (int i = 0; i < 16; ++i) {
        const int c = i*4 + g;
        t[c][wv] = x[((size_t)n*CIN + c)*HWSZ + hw0 + wv];
    }
    __syncthreads();
    #pragma unroll
    for (int i = 0; i < 4; ++i) {
        const int unit = i*256 + tid;
        const int cg = unit & 15;
        const int hw = unit >> 4;
        uint2 o;
        o.x = pk2bf(t[cg*4+0][hw], t[cg*4+1][hw]);
        o.y = pk2bf(t[cg*4+2][hw], t[cg*4+3][hw]);
        *(uint2*)(xt + ((size_t)n*HWSZ + hw0 + hw)*CIN + cg*4) = o;
    }
}

// ---------- prep 2: weights -> bf16 A-fragment swizzle (k = t*64+c) ----------
__global__ __launch_bounds__(256) void wswz_k(
    const float* __restrict__ wgt, const float* __restrict__ offw,
    u16* __restrict__ wswz, u16* __restrict__ oswz)
{
    const int gid = blockIdx.x * 256 + threadIdx.x;
    if (gid < WSWZ_ELEMS) {
        const int j = gid & 7, o = (gid >> 3) & 63, q = (gid >> 9) & 3, s = gid >> 11;
        const int k = s*32 + q*8 + j;
        const int c = k & 63, t = k >> 6;
        wswz[gid] = f2bf(wgt[o*576 + c*9 + t]);
    } else {
        const int g2 = gid - WSWZ_ELEMS;
        const int j = g2 & 7, r = (g2 >> 3) & 31, q = (g2 >> 8) & 3, s = g2 >> 10;
        const int k = s*32 + q*8 + j;
        const int c = k & 63, t = k >> 6;
        oswz[g2] = (r < 27) ? f2bf(offw[r*576 + c*9 + t]) : (u16)0;
    }
}

// ---------- fused: offset conv + sampling + main conv, one wave = 16 positions ----------
__global__ __launch_bounds__(256, 4) void dcn_k(
    const u16*  __restrict__ xt,
    const u16*  __restrict__ wswz,
    const u16*  __restrict__ oswz,
    const float* __restrict__ bias,
    const float* __restrict__ offb,
    float* __restrict__ out)
{
    __shared__ float raws[4][32][16];
    __shared__ uint4 prm[4][9][16];

    const int tid  = threadIdx.x;
    const int lane = tid & 63;
    const int wid  = tid >> 6;
    const int m    = lane & 15;
    const int q    = lane >> 4;

    const int n     = blockIdx.x & 7;                     // XCD-locality swizzle
    const int rem64 = ((blockIdx.x >> 3)*4 + wid) * 16;   // 16 positions, one row
    const int ho  = rem64 / WW;
    const int wo0 = rem64 - ho*WW;
    const u16* xtn = xt + (size_t)n * HWSZ * CIN;

    // ---- phase 1: im2col B-fragment loads (regular grid, zero-padded) ----
    uint4 bu[18];
    #pragma unroll
    for (int s = 0; s < 18; ++s) {
        const int t  = s >> 1;
        const int ty = t / 3, tx = t - 3*ty;
        const int y  = ho - 1 + ty;
        const int xx = wo0 + m - 1 + tx;
        const int ch = (s & 1)*32 + q*8;
        uint4 v = {0u,0u,0u,0u};
        if (((unsigned)y < HH) && ((unsigned)xx < WW))
            v = *(const uint4*)(xtn + (y*WW + xx)*CIN + ch);
        bu[s] = v;
    }

    // ---- phase 2: offset conv (27 channels, rows padded to 32) ----
    {
        floatx4 acc0 = {0.f,0.f,0.f,0.f}, acc1 = {0.f,0.f,0.f,0.f};
        #pragma unroll
        for (int s = 0; s < 18; ++s) {
            CV cb; cb.u = bu[s];
            const u16* ap = oswz + (s*4 + q)*256 + m*8;
            acc0 = __builtin_amdgcn_mfma_f32_16x16x32_bf16(*(const short8*)(ap),       cb.s, acc0, 0, 0, 0);
            acc1 = __builtin_amdgcn_mfma_f32_16x16x32_bf16(*(const short8*)(ap + 128), cb.s, acc1, 0, 0, 0);
        }
        #pragma unroll
        for (int r = 0; r < 4; ++r) {
            raws[wid][q*4 + r][m]      = acc0[r];
            raws[wid][16 + q*4 + r][m] = acc1[r];
        }
    }
    __syncthreads();

    // ---- phase 3: packed tap params (mask & border zeroing folded into weights) ----
    #pragma unroll
    for (int i = 0; i < 3; ++i) {
        const int e = i*64 + lane;
        if (e < 144) {
            const int t = e >> 4;        // 0..8
            const int p = e & 15;
            const int ty = t / 3, tx = t - 3*ty;
            const float py = raws[wid][2*t][p]     + offb[2*t]     + (float)(ho - 1 + ty);
            const float px = raws[wid][2*t + 1][p] + offb[2*t + 1] + (float)(wo0 + p - 1 + tx);
            const float mk = 1.f / (1.f + expf(-(raws[wid][18 + t][p] + offb[18 + t])));
            const float y0f = floorf(py), x0f = floorf(px);
            const float fy = py - y0f, fx = px - x0f;
            const int y0 = (int)y0f, x0 = (int)x0f;
            const float gy = 1.f - fy, gx = 1.f - fx;
            const bool vy0 = (unsigned)y0       < HH;
            const bool vy1 = (unsigned)(y0 + 1) < HH;
            const bool vx0 = (unsigned)x0       < WW;
            const bool vx1 = (unsigned)(x0 + 1) < WW;
            const float w00 = (vy0 && vx0) ? gy*gx*mk : 0.f;
            const float w01 = (vy0 && vx1) ? gy*fx*mk : 0.f;
            const float w10 = (vy1 && vx0) ? fy*gx*mk : 0.f;
            const float w11 = (vy1 && vx1) ? fy*fx*mk : 0.f;
            const int yc0 = min(max(y0, 0), HH-1),  yc1 = min(max(y0+1, 0), HH-1);
            const int xc0 = min(max(x0, 0), WW-1),  xc1 = min(max(x0+1, 0), WW-1);
            const unsigned o00 = (unsigned)((yc0*WW + xc0)*CIN);
            const unsigned dxb = (unsigned)(xc1 - xc0);   // 0/1
            const unsigned dyb = (unsigned)(yc1 - yc0);   // 0/1
            uint4 P;
            P.x = o00 | (dxb << 30) | (dyb << 31);
            P.y = (unsigned)__half_as_ushort(__float2half(w00))
                | ((unsigned)__half_as_ushort(__float2half(w01)) << 16);
            P.z = (unsigned)__half_as_ushort(__float2half(w10))
                | ((unsigned)__half_as_ushort(__float2half(w11)) << 16);
            P.w = 0u;
            prm[wid][t][p] = P;
        }
    }
    __syncthreads();

    // ---- phase 4: pipelined gather + lerp + main MFMA (ping-pong half-steps) ----
    floatx4 acc[4];
    #pragma unroll
    for (int i = 0; i < 4; ++i) acc[i] = (floatx4){0.f,0.f,0.f,0.f};

    const int ch0 = q*8, ch1 = 32 + q*8;
    uint4 c0[4], c1[4];

    Tap tc = unpackP(prm[wid][0][m]);
    c0[0] = *(const uint4*)(xtn + tc.o00 + ch0);
    c0[1] = *(const uint4*)(xtn + tc.o01 + ch0);
    c0[2] = *(const uint4*)(xtn + tc.o10 + ch0);
    c0[3] = *(const uint4*)(xtn + tc.o11 + ch0);
    c1[0] = *(const uint4*)(xtn + tc.o00 + ch1);
    c1[1] = *(const uint4*)(xtn + tc.o01 + ch1);
    c1[2] = *(const uint4*)(xtn + tc.o10 + ch1);
    c1[3] = *(const uint4*)(xtn + tc.o11 + ch1);
    Tap tn = unpackP(prm[wid][1][m]);

    #pragma unroll
    for (int t = 0; t < 9; ++t) {
        // --- half-step s = 2t (channels 0..31): consume c0 ---
        {
            const uint4 r00 = c0[0], r01 = c0[1], r10 = c0[2], r11 = c0[3];
            const float w00 = tc.w00, w01 = tc.w01, w10 = tc.w10, w11 = tc.w11;
            float v0 = w00*BLO(r00.x) + w01*BLO(r01.x) + w10*BLO(r10.x) + w11*BLO(r11.x);
            float v1 = w00*BHI(r00.x) + w01*BHI(r01.x) + w10*BHI(r10.x) + w11*BHI(r11.x);
            float v2 = w00*BLO(r00.y) + w01*BLO(r01.y) + w10*BLO(r10.y) + w11*BLO(r11.y);
            float v3 = w00*BHI(r00.y) + w01*BHI(r01.y) + w10*BHI(r10.y) + w11*BHI(r11.y);
            float v4 = w00*BLO(r00.z) + w01*BLO(r01.z) + w10*BLO(r10.z) + w11*BLO(r11.z);
            float v5 = w00*BHI(r00.z) + w01*BHI(r01.z) + w10*BHI(r10.z) + w11*BHI(r11.z);
            float v6 = w00*BLO(r00.w) + w01*BLO(r01.w) + w10*BLO(r10.w) + w11*BLO(r11.w);
            float v7 = w00*BHI(r00.w) + w01*BHI(r01.w) + w10*BHI(r10.w) + w11*BHI(r11.w);
            CV cb;
            cb.u.x = pk2bf(v0, v1); cb.u.y = pk2bf(v2, v3);
            cb.u.z = pk2bf(v4, v5); cb.u.w = pk2bf(v6, v7);
            const u16* wp = wswz + ((2*t)*4 + q)*512 + m*8;
            acc[0] = __builtin_amdgcn_mfma_f32_16x16x32_bf16(*(const short8*)(wp),       cb.s, acc[0], 0, 0, 0);
            acc[1] = __builtin_amdgcn_mfma_f32_16x16x32_bf16(*(const short8*)(wp + 128), cb.s, acc[1], 0, 0, 0);
            acc[2] = __builtin_amdgcn_mfma_f32_16x16x32_bf16(*(const short8*)(wp + 256), cb.s, acc[2], 0, 0, 0);
            acc[3] = __builtin_amdgcn_mfma_f32_16x16x32_bf16(*(const short8*)(wp + 384), cb.s, acc[3], 0, 0, 0);
        }
        // refill c0 with tap t+1, channels 0..31
        if (t < 8) {
            c0[0] = *(const uint4*)(xtn + tn.o00 + ch0);
            c0[1] = *(const uint4*)(xtn + tn.o01 + ch0);
            c0[2] = *(const uint4*)(xtn + tn.o10 + ch0);
            c0[3] = *(const uint4*)(xtn + tn.o11 + ch0);
        }
        // --- half-step s = 2t+1 (channels 32..63): consume c1 ---
        {
            const uint4 r00 = c1[0], r01 = c1[1], r10 = c1[2], r11 = c1[3];
            const float w00 = tc.w00, w01 = tc.w01, w10 = tc.w10, w11 = tc.w11;
            float v0 = w00*BLO(r00.x) + w01*BLO(r01.x) + w10*BLO(r10.x) + w11*BLO(r11.x);
            float v1 = w00*BHI(r00.x) + w01*BHI(r01.x) + w10*BHI(r10.x) + w11*BHI(r11.x);
            float v2 = w00*BLO(r00.y) + w01*BLO(r01.y) + w10*BLO(r10.y) + w11*BLO(r11.y);
            float v3 = w00*BHI(r00.y) + w01*BHI(r01.y) + w10*BHI(r10.y) + w11*BHI(r11.y);
            float v4 = w00*BLO(r00.z) + w01*BLO(r01.z) + w10*BLO(r10.z) + w11*BLO(r11.z);
            float v5 = w00*BHI(r00.z) + w01*BHI(r01.z) + w10*BHI(r10.z) + w11*BHI(r11.z);
            float v6 = w00*BLO(r00.w) + w01*BLO(r01.w) + w10*BLO(r10.w) + w11*BLO(r11.w);
            float v7 = w00*BHI(r00.w) + w01*BHI(r01.w) + w10*BHI(r10.w) + w11*BHI(r11.w);
            CV cb;
            cb.u.x = pk2bf(v0, v1); cb.u.y = pk2bf(v2, v3);
            cb.u.z = pk2bf(v4, v5); cb.u.w = pk2bf(v6, v7);
            const u16* wp = wswz + ((2*t+1)*4 + q)*512 + m*8;
            acc[0] = __builtin_amdgcn_mfma_f32_16x16x32_bf16(*(const short8*)(wp),       cb.s, acc[0], 0, 0, 0);
            acc[1] = __builtin_amdgcn_mfma_f32_16x16x32_bf16(*(const short8*)(wp + 128), cb.s, acc[1], 0, 0, 0);
            acc[2] = __builtin_amdgcn_mfma_f32_16x16x32_bf16(*(const short8*)(wp + 256), cb.s, acc[2], 0, 0, 0);
            acc[3] = __builtin_amdgcn_mfma_f32_16x16x32_bf16(*(const short8*)(wp + 384), cb.s, acc[3], 0, 0, 0);
        }
        // refill c1 with tap t+1, channels 32..63; advance tap params
        if (t < 8) {
            c1[0] = *(const uint4*)(xtn + tn.o00 + ch1);
            c1[1] = *(const uint4*)(xtn + tn.o01 + ch1);
            c1[2] = *(const uint4*)(xtn + tn.o10 + ch1);
            c1[3] = *(const uint4*)(xtn + tn.o11 + ch1);
            tc = tn;
            if (t < 7) tn = unpackP(prm[wid][t+2][m]);
        }
    }

    // ---- epilogue ----
    #pragma unroll
    for (int ob = 0; ob < 4; ++ob) {
        #pragma unroll
        for (int r = 0; r < 4; ++r) {
            const int o = ob*16 + q*4 + r;
            out[(((size_t)n*OC + o)*HH + ho)*WW + wo0 + m] = acc[ob][r] + bias[o];
        }
    }
}

extern "C" void kernel_launch(void* const* d_in, const int* in_sizes, int n_in,
                              void* d_out, int out_size, void* d_ws, size_t ws_size,
                              hipStream_t stream)
{
    const float* x    = (const float*)d_in[0];
    const float* wgt  = (const float*)d_in[1];
    const float* bias = (const float*)d_in[2];
    const float* offw = (const float*)d_in[3];
    const float* offb = (const float*)d_in[4];
    float* out = (float*)d_out;

    u16* xt   = (u16*)d_ws;
    u16* wswz = xt + XT_ELEMS;
    u16* oswz = wswz + WSWZ_ELEMS;

    transpose_k<<<dim3(HWSZ/64, NB), 256, 0, stream>>>(x, xt);
    wswz_k<<<dim3((WSWZ_ELEMS + OSWZ_ELEMS)/256), 256, 0, stream>>>(wgt, offw, wswz, oswz);
    dcn_k<<<dim3(NPOS/64), 256, 0, stream>>>(xt, wswz, oswz, bias, offb, out);
}

// Round 8
// 174.876 us; speedup vs baseline: 2.1486x; 1.0041x over previous
//
#include <hip/hip_runtime.h>
#include <hip/hip_bf16.h>
#include <hip/hip_fp16.h>
#include <math.h>

#define NB  8
#define CIN 64
#define HH  112
#define WW  112
#define OC  64
#define HWSZ (HH*WW)
#define NPOS (NB*HWSZ)

typedef unsigned short u16;
typedef __attribute__((ext_vector_type(8))) short short8;
typedef __attribute__((ext_vector_type(4))) float floatx4;

#define XT_ELEMS   (NB*HWSZ*CIN)   // 6,422,528 u16 (12.25 MB)
#define WSWZ_ELEMS (18*4*64*8)     // 36,864 u16
#define OSWZ_ELEMS (18*4*32*8)     // 18,432 u16

__device__ __forceinline__ u16 f2bf(float f) {
    unsigned int i = __float_as_uint(f);
    unsigned int r = i + 0x7fffu + ((i >> 16) & 1u);   // RNE
    return (u16)(r >> 16);
}
__device__ __forceinline__ unsigned pk2bf(float lo, float hi) {
    union { __hip_bfloat162 b; unsigned u; } cv;
    cv.b = __float22bfloat162_rn(float2{lo, hi});      // v_cvt_pk_bf16_f32
    return cv.u;
}
#define BLO(uu) __uint_as_float((uu) << 16)
#define BHI(uu) __uint_as_float((uu) & 0xffff0000u)

union CV { uint4 u; short8 s; };

struct Tap { int o00, o01, o10, o11; float w00, w01, w10, w11; };

__device__ __forceinline__ Tap unpackP(uint4 P) {
    Tap t;
    const int o00 = (int)(P.x & 0xFFFFFu);
    const int dx  = (int)((P.x >> 30) & 1u) << 6;      // 0 or 64  (=CIN)
    const int dy  = (int)(P.x >> 31) * (WW*CIN);       // 0 or 7168
    t.o00 = o00; t.o01 = o00 + dx; t.o10 = o00 + dy; t.o11 = o00 + dx + dy;
    t.w00 = __half2float(__ushort_as_half((u16)(P.y & 0xFFFFu)));
    t.w01 = __half2float(__ushort_as_half((u16)(P.y >> 16)));
    t.w10 = __half2float(__ushort_as_half((u16)(P.z & 0xFFFFu)));
    t.w11 = __half2float(__ushort_as_half((u16)(P.z >> 16)));
    return t;
}

// ---------- prep 1: NCHW fp32 -> NHWC bf16 transpose of x ----------
__global__ __launch_bounds__(256) void transpose_k(
    const float* __restrict__ x, u16* __restrict__ xt)
{
    __shared__ float t[64][65];
    const int n   = blockIdx.y;
    const int hw0 = blockIdx.x * 64;
    const int tid = threadIdx.x;
    const int wv  = tid & 63;
    const int g   = tid >> 6;
    #pragma unroll
    for (int i = 0; i < 16; ++i) {
        const int c = i*4 + g;
        t[c][wv] = x[((size_t)n*CIN + c)*HWSZ + hw0 + wv];
    }
    __syncthreads();
    #pragma unroll
    for (int i = 0; i < 4; ++i) {
        const int unit = i*256 + tid;
        const int cg = unit & 15;
        const int hw = unit >> 4;
        uint2 o;
        o.x = pk2bf(t[cg*4+0][hw], t[cg*4+1][hw]);
        o.y = pk2bf(t[cg*4+2][hw], t[cg*4+3][hw]);
        *(uint2*)(xt + ((size_t)n*HWSZ + hw0 + hw)*CIN + cg*4) = o;
    }
}

// ---------- prep 2: weights -> bf16 A-fragment swizzle (k = t*64+c) ----------
__global__ __launch_bounds__(256) void wswz_k(
    const float* __restrict__ wgt, const float* __restrict__ offw,
    u16* __restrict__ wswz, u16* __restrict__ oswz)
{
    const int gid = blockIdx.x * 256 + threadIdx.x;
    if (gid < WSWZ_ELEMS) {
        const int j = gid & 7, o = (gid >> 3) & 63, q = (gid >> 9) & 3, s = gid >> 11;
        const int k = s*32 + q*8 + j;
        const int c = k & 63, t = k >> 6;
        wswz[gid] = f2bf(wgt[o*576 + c*9 + t]);
    } else {
        const int g2 = gid - WSWZ_ELEMS;
        const int j = g2 & 7, r = (g2 >> 3) & 31, q = (g2 >> 8) & 3, s = g2 >> 10;
        const int k = s*32 + q*8 + j;
        const int c = k & 63, t = k >> 6;
        oswz[g2] = (r < 27) ? f2bf(offw[r*576 + c*9 + t]) : (u16)0;
    }
}

#define IM2COL_LOAD(DST, S_) { \
    const int t_ = (S_) >> 1; \
    const int ty_ = t_/3, tx_ = t_ - 3*ty_; \
    const int y_ = ho - 1 + ty_, xx_ = wo0 + m - 1 + tx_; \
    const int ch_ = ((S_) & 1)*32 + q*8; \
    uint4 v_ = {0u,0u,0u,0u}; \
    if (((unsigned)y_ < HH) && ((unsigned)xx_ < WW)) \
        v_ = *(const uint4*)(xtn + (y_*WW + xx_)*CIN + ch_); \
    DST = v_; }

#define OFF_MFMA(SRC, S_) { CV cb_; cb_.u = (SRC); \
    const u16* ap_ = oswz + ((S_)*4 + q)*256 + m*8; \
    acc0 = __builtin_amdgcn_mfma_f32_16x16x32_bf16(*(const short8*)(ap_),       cb_.s, acc0, 0, 0, 0); \
    acc1 = __builtin_amdgcn_mfma_f32_16x16x32_bf16(*(const short8*)(ap_ + 128), cb_.s, acc1, 0, 0, 0); }

#define GATHER4(DST, I0, TAP, CH) { \
    DST[(I0)+0] = *(const uint4*)(xtn + (TAP).o00 + (CH)); \
    DST[(I0)+1] = *(const uint4*)(xtn + (TAP).o01 + (CH)); \
    DST[(I0)+2] = *(const uint4*)(xtn + (TAP).o10 + (CH)); \
    DST[(I0)+3] = *(const uint4*)(xtn + (TAP).o11 + (CH)); }

#define HALF_STEP(R00, R01, R10, R11, TP, S_) { \
    const float w00 = (TP).w00, w01 = (TP).w01, w10 = (TP).w10, w11 = (TP).w11; \
    float v0 = w00*BLO((R00).x) + w01*BLO((R01).x) + w10*BLO((R10).x) + w11*BLO((R11).x); \
    float v1 = w00*BHI((R00).x) + w01*BHI((R01).x) + w10*BHI((R10).x) + w11*BHI((R11).x); \
    float v2 = w00*BLO((R00).y) + w01*BLO((R01).y) + w10*BLO((R10).y) + w11*BLO((R11).y); \
    float v3 = w00*BHI((R00).y) + w01*BHI((R01).y) + w10*BHI((R10).y) + w11*BHI((R11).y); \
    float v4 = w00*BLO((R00).z) + w01*BLO((R01).z) + w10*BLO((R10).z) + w11*BLO((R11).z); \
    float v5 = w00*BHI((R00).z) + w01*BHI((R01).z) + w10*BHI((R10).z) + w11*BHI((R11).z); \
    float v6 = w00*BLO((R00).w) + w01*BLO((R01).w) + w10*BLO((R10).w) + w11*BLO((R11).w); \
    float v7 = w00*BHI((R00).w) + w01*BHI((R01).w) + w10*BHI((R10).w) + w11*BHI((R11).w); \
    CV cb_; \
    cb_.u.x = pk2bf(v0, v1); cb_.u.y = pk2bf(v2, v3); \
    cb_.u.z = pk2bf(v4, v5); cb_.u.w = pk2bf(v6, v7); \
    const u16* wp_ = wswz + ((S_)*4 + q)*512 + m*8; \
    acc[0] = __builtin_amdgcn_mfma_f32_16x16x32_bf16(*(const short8*)(wp_),       cb_.s, acc[0], 0, 0, 0); \
    acc[1] = __builtin_amdgcn_mfma_f32_16x16x32_bf16(*(const short8*)(wp_ + 128), cb_.s, acc[1], 0, 0, 0); \
    acc[2] = __builtin_amdgcn_mfma_f32_16x16x32_bf16(*(const short8*)(wp_ + 256), cb_.s, acc[2], 0, 0, 0); \
    acc[3] = __builtin_amdgcn_mfma_f32_16x16x32_bf16(*(const short8*)(wp_ + 384), cb_.s, acc[3], 0, 0, 0); }

// ---------- fused: offset conv + sampling + main conv ----------
__global__ __launch_bounds__(256)
__attribute__((amdgpu_waves_per_eu(2, 4)))
void dcn_k(
    const u16*  __restrict__ xt,
    const u16*  __restrict__ wswz,
    const u16*  __restrict__ oswz,
    const float* __restrict__ bias,
    const float* __restrict__ offb,
    float* __restrict__ out)
{
    __shared__ float raws[4][32][16];
    __shared__ uint4 prm[4][9][16];

    const int tid  = threadIdx.x;
    const int lane = tid & 63;
    const int wid  = tid >> 6;
    const int m    = lane & 15;
    const int q    = lane >> 4;

    const int n     = blockIdx.x & 7;                     // XCD-locality swizzle
    const int rem64 = ((blockIdx.x >> 3)*4 + wid) * 16;   // 16 positions, one row
    const int ho  = rem64 / WW;
    const int wo0 = rem64 - ho*WW;
    const u16* xtn = xt + (size_t)n * HWSZ * CIN;

    // ---- phase 1+2: im2col loads pipelined against offset-conv MFMAs ----
    {
        uint4 buA[6], buB[6];
        #pragma unroll
        for (int s = 0; s < 6; ++s) IM2COL_LOAD(buA[s], s)
        #pragma unroll
        for (int s = 0; s < 6; ++s) IM2COL_LOAD(buB[s], s + 6)

        floatx4 acc0 = {0.f,0.f,0.f,0.f}, acc1 = {0.f,0.f,0.f,0.f};
        #pragma unroll
        for (int s = 0; s < 6; ++s) {
            uint4 nv; IM2COL_LOAD(nv, s + 12)
            OFF_MFMA(buA[s], s)
            buA[s] = nv;
        }
        #pragma unroll
        for (int s = 0; s < 6; ++s) OFF_MFMA(buB[s], s + 6)
        #pragma unroll
        for (int s = 0; s < 6; ++s) OFF_MFMA(buA[s], s + 12)

        #pragma unroll
        for (int r = 0; r < 4; ++r) {
            raws[wid][q*4 + r][m]      = acc0[r];
            raws[wid][16 + q*4 + r][m] = acc1[r];
        }
    }
    __syncthreads();

    // ---- phase 3: packed tap params (mask & border zeroing folded into weights) ----
    #pragma unroll
    for (int i = 0; i < 3; ++i) {
        const int e = i*64 + lane;
        if (e < 144) {
            const int t = e >> 4;        // 0..8
            const int p = e & 15;
            const int ty = t / 3, tx = t - 3*ty;
            const float py = raws[wid][2*t][p]     + offb[2*t]     + (float)(ho - 1 + ty);
            const float px = raws[wid][2*t + 1][p] + offb[2*t + 1] + (float)(wo0 + p - 1 + tx);
            const float mk = 1.f / (1.f + expf(-(raws[wid][18 + t][p] + offb[18 + t])));
            const float y0f = floorf(py), x0f = floorf(px);
            const float fy = py - y0f, fx = px - x0f;
            const int y0 = (int)y0f, x0 = (int)x0f;
            const float gy = 1.f - fy, gx = 1.f - fx;
            const bool vy0 = (unsigned)y0       < HH;
            const bool vy1 = (unsigned)(y0 + 1) < HH;
            const bool vx0 = (unsigned)x0       < WW;
            const bool vx1 = (unsigned)(x0 + 1) < WW;
            const float w00 = (vy0 && vx0) ? gy*gx*mk : 0.f;
            const float w01 = (vy0 && vx1) ? gy*fx*mk : 0.f;
            const float w10 = (vy1 && vx0) ? fy*gx*mk : 0.f;
            const float w11 = (vy1 && vx1) ? fy*fx*mk : 0.f;
            const int yc0 = min(max(y0, 0), HH-1),  yc1 = min(max(y0+1, 0), HH-1);
            const int xc0 = min(max(x0, 0), WW-1),  xc1 = min(max(x0+1, 0), WW-1);
            const unsigned o00 = (unsigned)((yc0*WW + xc0)*CIN);
            const unsigned dxb = (unsigned)(xc1 - xc0);   // 0/1
            const unsigned dyb = (unsigned)(yc1 - yc0);   // 0/1
            uint4 P;
            P.x = o00 | (dxb << 30) | (dyb << 31);
            P.y = (unsigned)__half_as_ushort(__float2half(w00))
                | ((unsigned)__half_as_ushort(__float2half(w01)) << 16);
            P.z = (unsigned)__half_as_ushort(__float2half(w10))
                | ((unsigned)__half_as_ushort(__float2half(w11)) << 16);
            P.w = 0u;
            prm[wid][t][p] = P;
        }
    }
    __syncthreads();

    // ---- phase 4: 2-tap-deep pipelined gather + lerp + main MFMA ----
    floatx4 acc[4];
    #pragma unroll
    for (int i = 0; i < 4; ++i) acc[i] = (floatx4){0.f,0.f,0.f,0.f};

    const int ch0 = q*8, ch1 = 32 + q*8;
    uint4 G[2][8];
    Tap   tp[2];

    tp[0] = unpackP(prm[wid][0][m]);
    GATHER4(G[0], 0, tp[0], ch0)
    GATHER4(G[0], 4, tp[0], ch1)
    tp[1] = unpackP(prm[wid][1][m]);
    GATHER4(G[1], 0, tp[1], ch0)
    GATHER4(G[1], 4, tp[1], ch1)
    uint4 Pn = prm[wid][2][m];          // raw prm for tap t+2, one tap ahead

    #pragma unroll
    for (int t = 0; t < 9; ++t) {
        const int cur = t & 1;
        // half A: channels 0..31 of tap t
        HALF_STEP(G[cur][0], G[cur][1], G[cur][2], G[cur][3], tp[cur], 2*t)
        Tap tn2;
        if (t < 7) {
            tn2 = unpackP(Pn);
            GATHER4(G[cur], 0, tn2, ch0)   // refill for tap t+2
        }
        // half B: channels 32..63 of tap t
        HALF_STEP(G[cur][4], G[cur][5], G[cur][6], G[cur][7], tp[cur], 2*t + 1)
        if (t < 7) {
            GATHER4(G[cur], 4, tn2, ch1)
            tp[cur] = tn2;
            if (t < 6) Pn = prm[wid][t + 3][m];
        }
    }

    // ---- epilogue ----
    #pragma unroll
    for (int ob = 0; ob < 4; ++ob) {
        #pragma unroll
        for (int r = 0; r < 4; ++r) {
            const int o = ob*16 + q*4 + r;
            out[(((size_t)n*OC + o)*HH + ho)*WW + wo0 + m] = acc[ob][r] + bias[o];
        }
    }
}

extern "C" void kernel_launch(void* const* d_in, const int* in_sizes, int n_in,
                              void* d_out, int out_size, void* d_ws, size_t ws_size,
                              hipStream_t stream)
{
    const float* x    = (const float*)d_in[0];
    const float* wgt  = (const float*)d_in[1];
    const float* bias = (const float*)d_in[2];
    const float* offw = (const float*)d_in[3];
    const float* offb = (const float*)d_in[4];
    float* out = (float*)d_out;

    u16* xt   = (u16*)d_ws;
    u16* wswz = xt + XT_ELEMS;
    u16* oswz = wswz + WSWZ_ELEMS;

    transpose_k<<<dim3(HWSZ/64, NB), 256, 0, stream>>>(x, xt);
    wswz_k<<<dim3((WSWZ_ELEMS + OSWZ_ELEMS)/256), 256, 0, stream>>>(wgt, offw, wswz, oswz);
    dcn_k<<<dim3(NPOS/64), 256, 0, stream>>>(xt, wswz, oswz, bias, offb, out);
}